// Round 1
// baseline (3722.176 us; speedup 1.0000x reference)
//
#include <hip/hip_runtime.h>
#include <math.h>

static constexpr int NN   = 100000;   // nodes
static constexpr int NE   = 3200000;  // edges (before self loops)
static constexpr int ET   = NE + NN;  // edges incl self loops
static constexpr int DIN  = 128;
static constexpr int H1   = 8;        // heads layer 1
static constexpr int F1   = 4;        // per-head feats layer 1
static constexpr int C1   = 32;       // H1*F1
static constexpr int DOUT = 64;
static constexpr int NG   = 64;       // graphs

__device__ __forceinline__ float lrelu(float x){ return x > 0.f ? x : 0.2f*x; }
// monotonic float->signed-int key so atomicMax(int) implements float max
__device__ __forceinline__ int   fkey(float x){ int i = __float_as_int(x); return i >= 0 ? i : (i ^ 0x7fffffff); }
__device__ __forceinline__ float funkey(int k){ return __int_as_float(k >= 0 ? k : (k ^ 0x7fffffff)); }

__device__ __forceinline__ void edge_sd(const int* __restrict__ ei, int e, int& s, int& d){
  if (e < NE) { s = ei[e]; d = ei[NE + e]; }
  else        { int n = e - NE; s = n; d = n; }   // appended self loops
}

// ---------------- layer 1 ----------------

__global__ __launch_bounds__(256) void k_gemm1(const float* __restrict__ x,
                                               const float* __restrict__ W,
                                               float* __restrict__ h1){
  __shared__ float w[DIN * C1];
  for (int i = threadIdx.x; i < DIN * C1; i += 256) w[i] = W[i];
  __syncthreads();
  int idx = blockIdx.x * 256 + threadIdx.x;
  if (idx >= NN * C1) return;
  int n = idx >> 5, j = idx & 31;
  const float* xr = x + (size_t)n * DIN;
  float acc = 0.f;
  #pragma unroll
  for (int k = 0; k < DIN; ++k) acc += xr[k] * w[k * C1 + j];
  h1[idx] = acc;
}

__global__ __launch_bounds__(256) void k_att1(const float* __restrict__ h1,
                                              const float* __restrict__ as,
                                              const float* __restrict__ ad,
                                              float* __restrict__ a_s,
                                              float* __restrict__ a_d){
  int idx = blockIdx.x * 256 + threadIdx.x;
  if (idx >= NN * H1) return;
  int n = idx >> 3, h = idx & 7;
  const float* hr = h1 + (size_t)n * C1 + h * F1;
  float s = 0.f, d = 0.f;
  #pragma unroll
  for (int f = 0; f < F1; ++f){ s += hr[f] * as[h * F1 + f]; d += hr[f] * ad[h * F1 + f]; }
  a_s[idx] = s; a_d[idx] = d;
}

__global__ __launch_bounds__(256) void k_init_amax(int* __restrict__ amax1, int* __restrict__ amax2){
  int idx = blockIdx.x * 256 + threadIdx.x;
  if (idx < NN * H1) amax1[idx] = INT_MIN;
  else if (idx < NN * (H1 + 1)) amax2[idx - NN * H1] = INT_MIN;
}

__global__ __launch_bounds__(256) void k_e1_max(const int* __restrict__ ei,
                                                const float* __restrict__ a_s, const float* __restrict__ a_d,
                                                int* __restrict__ amax){
  int idx = blockIdx.x * 256 + threadIdx.x;
  if (idx >= ET * H1) return;
  int e = idx >> 3, h = idx & 7;
  int s, d; edge_sd(ei, e, s, d);
  float al = lrelu(a_s[s * H1 + h] + a_d[d * H1 + h]);
  atomicMax(&amax[d * H1 + h], fkey(al));
}

__global__ __launch_bounds__(256) void k_e1_sum(const int* __restrict__ ei,
                                                const float* __restrict__ a_s, const float* __restrict__ a_d,
                                                const int* __restrict__ amax, float* __restrict__ denom){
  int idx = blockIdx.x * 256 + threadIdx.x;
  if (idx >= ET * H1) return;
  int e = idx >> 3, h = idx & 7;
  int s, d; edge_sd(ei, e, s, d);
  float al = lrelu(a_s[s * H1 + h] + a_d[d * H1 + h]);
  atomicAdd(&denom[d * H1 + h], expf(al - funkey(amax[d * H1 + h])));
}

__global__ __launch_bounds__(256) void k_e1_agg(const int* __restrict__ ei,
                                                const float* __restrict__ a_s, const float* __restrict__ a_d,
                                                const int* __restrict__ amax, const float* __restrict__ denom,
                                                const float* __restrict__ h1, float* __restrict__ out1){
  int idx = blockIdx.x * 256 + threadIdx.x;
  if (idx >= ET * H1) return;
  int e = idx >> 3, h = idx & 7;
  int s, d; edge_sd(ei, e, s, d);
  float al = lrelu(a_s[s * H1 + h] + a_d[d * H1 + h]);
  float wv = expf(al - funkey(amax[d * H1 + h])) / (denom[d * H1 + h] + 1e-16f);
  const float* hs = h1 + (size_t)s * C1 + h * F1;
  float* od = out1 + (size_t)d * C1 + h * F1;
  #pragma unroll
  for (int f = 0; f < F1; ++f) atomicAdd(&od[f], hs[f] * wv);
}

__global__ __launch_bounds__(256) void k_elu(const float* __restrict__ b1, float* __restrict__ out1){
  int idx = blockIdx.x * 256 + threadIdx.x;
  if (idx >= NN * C1) return;
  float v = out1[idx] + b1[idx & 31];
  out1[idx] = v > 0.f ? v : (expf(v) - 1.f);
}

// ---------------- layer 2 ----------------

__global__ __launch_bounds__(256) void k_gemm2(const float* __restrict__ hin,
                                               const float* __restrict__ W,
                                               float* __restrict__ h2){
  __shared__ float w[C1 * DOUT];
  for (int i = threadIdx.x; i < C1 * DOUT; i += 256) w[i] = W[i];
  __syncthreads();
  int idx = blockIdx.x * 256 + threadIdx.x;
  if (idx >= NN * DOUT) return;
  int n = idx >> 6, j = idx & 63;
  const float* hr = hin + (size_t)n * C1;
  float acc = 0.f;
  #pragma unroll
  for (int k = 0; k < C1; ++k) acc += hr[k] * w[k * DOUT + j];
  h2[idx] = acc;
}

__global__ __launch_bounds__(256) void k_att2(const float* __restrict__ h2,
                                              const float* __restrict__ as2, const float* __restrict__ ad2,
                                              float* __restrict__ a_s, float* __restrict__ a_d){
  int idx = blockIdx.x * 256 + threadIdx.x;
  int n = idx >> 6, j = idx & 63;
  if (n >= NN) return;
  float hv = h2[(size_t)n * DOUT + j];
  float s = hv * as2[j], d = hv * ad2[j];
  #pragma unroll
  for (int o = 32; o > 0; o >>= 1){ s += __shfl_down(s, o, 64); d += __shfl_down(d, o, 64); }
  if (j == 0){ a_s[n] = s; a_d[n] = d; }
}

__global__ __launch_bounds__(256) void k_e2_max(const int* __restrict__ ei,
                                                const float* __restrict__ a_s, const float* __restrict__ a_d,
                                                int* __restrict__ amax){
  int e = blockIdx.x * 256 + threadIdx.x;
  if (e >= ET) return;
  int s, d; edge_sd(ei, e, s, d);
  float al = lrelu(a_s[s] + a_d[d]);
  atomicMax(&amax[d], fkey(al));
}

__global__ __launch_bounds__(256) void k_e2_sum(const int* __restrict__ ei,
                                                const float* __restrict__ a_s, const float* __restrict__ a_d,
                                                const int* __restrict__ amax, float* __restrict__ denom){
  int e = blockIdx.x * 256 + threadIdx.x;
  if (e >= ET) return;
  int s, d; edge_sd(ei, e, s, d);
  float al = lrelu(a_s[s] + a_d[d]);
  atomicAdd(&denom[d], expf(al - funkey(amax[d])));
}

__global__ __launch_bounds__(256) void k_e2_agg(const int* __restrict__ ei,
                                                const float* __restrict__ a_s, const float* __restrict__ a_d,
                                                const int* __restrict__ amax, const float* __restrict__ denom,
                                                const float* __restrict__ h2, float* __restrict__ out2){
  long long idx = (long long)blockIdx.x * 256 + threadIdx.x;
  if (idx >= (long long)ET * DOUT) return;
  int e = (int)(idx >> 6), f = (int)(idx & 63);
  int s, d; edge_sd(ei, e, s, d);
  float al = lrelu(a_s[s] + a_d[d]);
  float wv = expf(al - funkey(amax[d])) / (denom[d] + 1e-16f);
  atomicAdd(&out2[(size_t)d * DOUT + f], h2[(size_t)s * DOUT + f] * wv);
}

// ---------------- pool ----------------

__global__ __launch_bounds__(256) void k_pool(const float* __restrict__ out2,
                                              const int* __restrict__ batch,
                                              float* __restrict__ sums, float* __restrict__ cnts){
  int idx = blockIdx.x * 256 + threadIdx.x;
  if (idx >= NN * DOUT) return;
  int n = idx >> 6, f = idx & 63;
  int g = batch[n];
  atomicAdd(&sums[g * DOUT + f], out2[idx]);
  if (f == 0) atomicAdd(&cnts[g], 1.f);
}

__global__ __launch_bounds__(256) void k_final(const float* __restrict__ sums,
                                               const float* __restrict__ cnts,
                                               const float* __restrict__ b2,
                                               float* __restrict__ out){
  int idx = blockIdx.x * 256 + threadIdx.x;
  if (idx >= NG * DOUT) return;
  int g = idx >> 6, f = idx & 63;
  out[idx] = sums[idx] / fmaxf(cnts[g], 1.f) + b2[f];
}

extern "C" void kernel_launch(void* const* d_in, const int* in_sizes, int n_in,
                              void* d_out, int out_size, void* d_ws, size_t ws_size,
                              hipStream_t stream) {
  const float* x   = (const float*)d_in[0];
  const int*   ei  = (const int*)  d_in[1];
  const int*   bat = (const int*)  d_in[2];
  const float* W1  = (const float*)d_in[3];
  const float* as1 = (const float*)d_in[4];
  const float* ad1 = (const float*)d_in[5];
  const float* b1  = (const float*)d_in[6];
  const float* W2  = (const float*)d_in[7];
  const float* as2 = (const float*)d_in[8];
  const float* ad2 = (const float*)d_in[9];
  const float* b2  = (const float*)d_in[10];
  float* out = (float*)d_out;

  float* p = (float*)d_ws;
  float* h1    = p; p += (size_t)NN * C1;
  float* a_s1  = p; p += (size_t)NN * H1;
  float* a_d1  = p; p += (size_t)NN * H1;
  float* h2    = p; p += (size_t)NN * DOUT;
  float* a_s2  = p; p += NN;
  float* a_d2  = p; p += NN;
  int*   amax1 = (int*)p; p += (size_t)NN * H1;
  int*   amax2 = (int*)p; p += NN;
  float* zbase = p;
  float* denom1 = p; p += (size_t)NN * H1;
  float* out1   = p; p += (size_t)NN * C1;
  float* denom2 = p; p += NN;
  float* out2   = p; p += (size_t)NN * DOUT;
  float* sums   = p; p += NG * DOUT;
  float* cnts   = p; p += NG;
  size_t zbytes = (size_t)(p - zbase) * sizeof(float);

  hipMemsetAsync(zbase, 0, zbytes, stream);
  k_init_amax<<<(NN * (H1 + 1) + 255) / 256, 256, 0, stream>>>(amax1, amax2);

  // layer 1
  k_gemm1<<<(NN * C1 + 255) / 256, 256, 0, stream>>>(x, W1, h1);
  k_att1 <<<(NN * H1 + 255) / 256, 256, 0, stream>>>(h1, as1, ad1, a_s1, a_d1);
  k_e1_max<<<(ET * H1 + 255) / 256, 256, 0, stream>>>(ei, a_s1, a_d1, amax1);
  k_e1_sum<<<(ET * H1 + 255) / 256, 256, 0, stream>>>(ei, a_s1, a_d1, amax1, denom1);
  k_e1_agg<<<(ET * H1 + 255) / 256, 256, 0, stream>>>(ei, a_s1, a_d1, amax1, denom1, h1, out1);
  k_elu  <<<(NN * C1 + 255) / 256, 256, 0, stream>>>(b1, out1);

  // layer 2
  k_gemm2<<<(NN * DOUT + 255) / 256, 256, 0, stream>>>(out1, W2, h2);
  k_att2 <<<(NN * DOUT + 255) / 256, 256, 0, stream>>>(h2, as2, ad2, a_s2, a_d2);
  k_e2_max<<<(ET + 255) / 256, 256, 0, stream>>>(ei, a_s2, a_d2, amax2);
  k_e2_sum<<<(ET + 255) / 256, 256, 0, stream>>>(ei, a_s2, a_d2, amax2, denom2);
  {
    long long tot = (long long)ET * DOUT;
    int blocks = (int)((tot + 255) / 256);
    k_e2_agg<<<blocks, 256, 0, stream>>>(ei, a_s2, a_d2, amax2, denom2, h2, out2);
  }

  // pool
  k_pool <<<(NN * DOUT + 255) / 256, 256, 0, stream>>>(out2, bat, sums, cnts);
  k_final<<<(NG * DOUT + 255) / 256, 256, 0, stream>>>(sums, cnts, b2, out);
}

// Round 2
// 1694.665 us; speedup vs baseline: 2.1964x; 2.1964x over previous
//
#include <hip/hip_runtime.h>
#include <math.h>

static constexpr int NN   = 100000;   // nodes
static constexpr int NE   = 3200000;  // edges (before self loops)
static constexpr int ET   = NE + NN;  // edges incl self loops
static constexpr int DIN  = 128;
static constexpr int H1   = 8;        // heads layer 1
static constexpr int F1   = 4;        // per-head feats layer 1
static constexpr int C1   = 32;       // H1*F1
static constexpr int DOUT = 64;
static constexpr int NG   = 64;       // graphs
static constexpr int NB_SCAN = (NN + 255) / 256;   // 391

__device__ __forceinline__ float lrelu(float x){ return x > 0.f ? x : 0.2f*x; }

__device__ __forceinline__ void edge_sd(const int* __restrict__ ei, int e, int& s, int& d){
  if (e < NE) { s = ei[e]; d = ei[NE + e]; }
  else        { int n = e - NE; s = n; d = n; }   // appended self loops
}

// ---------- GEMM1 (x@W1) fused with att1 dots ----------
__global__ __launch_bounds__(256) void k_gemm1(const float* __restrict__ x,
                                               const float* __restrict__ W,
                                               const float* __restrict__ as1,
                                               const float* __restrict__ ad1,
                                               float* __restrict__ h1,
                                               float* __restrict__ a_s,
                                               float* __restrict__ a_d){
  __shared__ float w[DIN * C1];
  for (int i = threadIdx.x; i < DIN * C1; i += 256) w[i] = W[i];
  __syncthreads();
  int idx = blockIdx.x * 256 + threadIdx.x;
  int n = idx >> 5, j = idx & 31;           // j = h*4+f
  const float* xr = x + (size_t)n * DIN;
  float acc = 0.f;
  #pragma unroll
  for (int k = 0; k < DIN; ++k) acc += xr[k] * w[k * C1 + j];
  h1[idx] = acc;
  float s = acc * as1[j], d = acc * ad1[j];
  s += __shfl_xor(s, 1, 64); s += __shfl_xor(s, 2, 64);
  d += __shfl_xor(d, 1, 64); d += __shfl_xor(d, 2, 64);
  if ((j & 3) == 0){ a_s[n * H1 + (j >> 2)] = s; a_d[n * H1 + (j >> 2)] = d; }
}

// ---------- counting sort of edges by dst ----------
__global__ __launch_bounds__(256) void k_hist(const int* __restrict__ ei, int* __restrict__ cnt){
  int e = blockIdx.x * 256 + threadIdx.x;
  if (e >= ET) return;
  int s, d; edge_sd(ei, e, s, d);
  atomicAdd(&cnt[d], 1);
}

__global__ __launch_bounds__(256) void k_scan_blk(const int* __restrict__ cnt,
                                                  int* __restrict__ tmp, int* __restrict__ btot){
  int g = blockIdx.x * 256 + threadIdx.x;
  int v = (g < NN) ? cnt[g] : 0;
  int lane = threadIdx.x & 63, wv = threadIdx.x >> 6;
  int xv = v;
  #pragma unroll
  for (int o = 1; o < 64; o <<= 1){ int y = __shfl_up(xv, o, 64); if (lane >= o) xv += y; }
  __shared__ int ws[4];
  if (lane == 63) ws[wv] = xv;
  __syncthreads();
  int off = 0;
  for (int i = 0; i < wv; ++i) off += ws[i];
  xv += off;
  if (g < NN) tmp[g] = xv;                        // inclusive within block
  if (threadIdx.x == 255) btot[blockIdx.x] = xv;  // block total
}

__global__ __launch_bounds__(512) void k_scan_top(int* __restrict__ btot){
  int t = threadIdx.x;
  int v = (t < NB_SCAN) ? btot[t] : 0;
  int lane = t & 63, wv = t >> 6;
  int xv = v;
  #pragma unroll
  for (int o = 1; o < 64; o <<= 1){ int y = __shfl_up(xv, o, 64); if (lane >= o) xv += y; }
  __shared__ int ws[8];
  if (lane == 63) ws[wv] = xv;
  __syncthreads();
  int off = 0;
  for (int i = 0; i < wv; ++i) off += ws[i];
  xv += off;
  if (t < NB_SCAN) btot[t] = xv - v;              // exclusive block prefix
}

__global__ __launch_bounds__(256) void k_scan_fin(const int* __restrict__ cnt,
                                                  const int* __restrict__ tmp,
                                                  const int* __restrict__ btot,
                                                  int* __restrict__ row, int* __restrict__ cur){
  int g = blockIdx.x * 256 + threadIdx.x;
  if (g < NN){
    int ex = tmp[g] - cnt[g] + btot[g >> 8];
    row[g] = ex; cur[g] = ex;
  } else if (g == NN){
    row[NN] = ET;
  }
}

__global__ __launch_bounds__(256) void k_scatter(const int* __restrict__ ei,
                                                 int* __restrict__ cur, int* __restrict__ ssrc){
  int e = blockIdx.x * 256 + threadIdx.x;
  if (e >= ET) return;
  int s, d; edge_sd(ei, e, s, d);
  int pos = atomicAdd(&cur[d], 1);
  ssrc[pos] = s;
}

// ---------- layer-1 aggregation: one half-wave (32 lanes) per node ----------
__global__ __launch_bounds__(256) void k_agg1(const int* __restrict__ row,
                                              const int* __restrict__ ssrc,
                                              const float* __restrict__ a_s,
                                              const float* __restrict__ a_d,
                                              const float* __restrict__ h1,
                                              const float* __restrict__ b1,
                                              float* __restrict__ out1){
  int wid  = (blockIdx.x * 256 + threadIdx.x) >> 6;
  int lane = threadIdx.x & 63;
  int node = wid * 2 + (lane >> 5);
  if (node >= NN) return;
  int l32 = lane & 31, h = l32 >> 2;
  float ad  = a_d[node * H1 + h];
  int beg = row[node], end = row[node + 1];
  float acc = 0.f, den = 0.f;
  for (int i = beg; i < end; ++i){
    int s = ssrc[i];
    float al = lrelu(a_s[s * H1 + h] + ad);
    float w  = __expf(al);
    den += w;
    acc += w * h1[s * C1 + l32];
  }
  float v = acc / den + b1[l32];
  out1[node * C1 + l32] = v > 0.f ? v : expm1f(v);   // fused bias + ELU
}

// ---------- GEMM2 (out1@W2) fused with att2 dots ----------
__global__ __launch_bounds__(256) void k_gemm2(const float* __restrict__ hin,
                                               const float* __restrict__ W,
                                               const float* __restrict__ as2,
                                               const float* __restrict__ ad2,
                                               float* __restrict__ h2,
                                               float* __restrict__ a_s,
                                               float* __restrict__ a_d){
  __shared__ float w[C1 * DOUT];
  for (int i = threadIdx.x; i < C1 * DOUT; i += 256) w[i] = W[i];
  __syncthreads();
  int idx = blockIdx.x * 256 + threadIdx.x;
  int n = idx >> 6, j = idx & 63;
  const float* hr = hin + (size_t)n * C1;
  float acc = 0.f;
  #pragma unroll
  for (int k = 0; k < C1; ++k) acc += hr[k] * w[k * DOUT + j];
  h2[idx] = acc;
  float s = acc * as2[j], d = acc * ad2[j];
  #pragma unroll
  for (int o = 1; o < 64; o <<= 1){ s += __shfl_xor(s, o, 64); d += __shfl_xor(d, o, 64); }
  if (j == 0){ a_s[n] = s; a_d[n] = d; }
}

// ---------- layer-2 aggregation + mean-pool scatter: one wave per node ----------
__global__ __launch_bounds__(256) void k_agg2(const int* __restrict__ row,
                                              const int* __restrict__ ssrc,
                                              const float* __restrict__ a_s,
                                              const float* __restrict__ a_d,
                                              const float* __restrict__ h2,
                                              const int* __restrict__ batch,
                                              float* __restrict__ sums,
                                              float* __restrict__ cntg){
  int node = (blockIdx.x * 256 + threadIdx.x) >> 6;
  int lane = threadIdx.x & 63;
  if (node >= NN) return;
  float ad  = a_d[node];
  int beg = row[node], end = row[node + 1];
  float acc = 0.f, den = 0.f;
  for (int i = beg; i < end; ++i){
    int s = ssrc[i];
    float al = lrelu(a_s[s] + ad);
    float w  = __expf(al);
    den += w;
    acc += w * h2[s * DOUT + lane];
  }
  float o = acc / den;
  int g = batch[node];
  atomicAdd(&sums[g * DOUT + lane], o);
  if (lane == 0) atomicAdd(&cntg[g], 1.f);
}

__global__ __launch_bounds__(256) void k_final(const float* __restrict__ sums,
                                               const float* __restrict__ cntg,
                                               const float* __restrict__ b2,
                                               float* __restrict__ out){
  int idx = blockIdx.x * 256 + threadIdx.x;
  if (idx >= NG * DOUT) return;
  int g = idx >> 6, f = idx & 63;
  out[idx] = sums[idx] / fmaxf(cntg[g], 1.f) + b2[f];
}

extern "C" void kernel_launch(void* const* d_in, const int* in_sizes, int n_in,
                              void* d_out, int out_size, void* d_ws, size_t ws_size,
                              hipStream_t stream) {
  const float* x   = (const float*)d_in[0];
  const int*   ei  = (const int*)  d_in[1];
  const int*   bat = (const int*)  d_in[2];
  const float* W1  = (const float*)d_in[3];
  const float* as1 = (const float*)d_in[4];
  const float* ad1 = (const float*)d_in[5];
  const float* b1  = (const float*)d_in[6];
  const float* W2  = (const float*)d_in[7];
  const float* as2 = (const float*)d_in[8];
  const float* ad2 = (const float*)d_in[9];
  const float* b2  = (const float*)d_in[10];
  float* out = (float*)d_out;

  float* p = (float*)d_ws;
  float* h1    = p; p += (size_t)NN * C1;       // 3.2M
  float* a_s1  = p; p += (size_t)NN * H1;       // 0.8M
  float* a_d1  = p; p += (size_t)NN * H1;
  float* out1  = p; p += (size_t)NN * C1;
  float* h2    = p; p += (size_t)NN * DOUT;     // 6.4M
  float* a_s2  = p; p += NN;
  float* a_d2  = p; p += NN;
  int*   row   = (int*)p; p += NN + 1;
  int*   cur   = (int*)p; p += NN;
  int*   tmp   = (int*)p; p += NN;
  int*   btot  = (int*)p; p += 512;
  int*   ssrc  = (int*)p; p += ET;              // 3.3M
  // zero-init region (histogram + pool accumulators)
  float* zbase = p;
  int*   cnt   = (int*)p; p += NN;
  float* sums  = p; p += NG * DOUT;
  float* cntg  = p; p += NG;
  size_t zbytes = (size_t)(p - zbase) * sizeof(float);

  hipMemsetAsync(zbase, 0, zbytes, stream);

  // node transforms
  k_gemm1<<<(NN * C1) / 256, 256, 0, stream>>>(x, W1, as1, ad1, h1, a_s1, a_d1);

  // counting sort by dst
  k_hist    <<<(ET + 255) / 256, 256, 0, stream>>>(ei, cnt);
  k_scan_blk<<<NB_SCAN, 256, 0, stream>>>(cnt, tmp, btot);
  k_scan_top<<<1, 512, 0, stream>>>(btot);
  k_scan_fin<<<(NN + 256) / 256, 256, 0, stream>>>(cnt, tmp, btot, row, cur);
  k_scatter <<<(ET + 255) / 256, 256, 0, stream>>>(ei, cur, ssrc);

  // layer 1 aggregate (+bias+ELU)
  k_agg1<<<(NN * 32) / 256, 256, 0, stream>>>(row, ssrc, a_s1, a_d1, h1, b1, out1);

  // layer 2
  k_gemm2<<<(NN * DOUT) / 256, 256, 0, stream>>>(out1, W2, as2, ad2, h2, a_s2, a_d2);
  k_agg2 <<<(NN * DOUT) / 256, 256, 0, stream>>>(row, ssrc, a_s2, a_d2, h2, bat, sums, cntg);

  // finalize pooled means
  k_final<<<(NG * DOUT + 255) / 256, 256, 0, stream>>>(sums, cntg, b2, out);
}

// Round 4
// 1507.839 us; speedup vs baseline: 2.4686x; 1.1239x over previous
//
#include <hip/hip_runtime.h>
#include <math.h>

static constexpr int NN   = 100000;   // nodes
static constexpr int NE   = 3200000;  // edges (before self loops)
static constexpr int ET   = NE + NN;  // edges incl self loops
static constexpr int DIN  = 128;
static constexpr int H1   = 8;        // heads layer 1
static constexpr int F1   = 4;        // per-head feats layer 1
static constexpr int C1   = 32;       // H1*F1
static constexpr int DOUT = 64;
static constexpr int NG   = 64;       // graphs
static constexpr int NB_SCAN = (NN + 255) / 256;   // 391

__device__ __forceinline__ float lrelu(float x){ return x > 0.f ? x : 0.2f*x; }

__device__ __forceinline__ void edge_sd(const int* __restrict__ ei, int e, int& s, int& d){
  if (e < NE) { s = ei[e]; d = ei[NE + e]; }
  else        { int n = e - NE; s = n; d = n; }   // appended self loops
}

// ---------- GEMM1 (x@W1) fused with att1 dots ----------
__global__ __launch_bounds__(256) void k_gemm1(const float* __restrict__ x,
                                               const float* __restrict__ W,
                                               const float* __restrict__ as1,
                                               const float* __restrict__ ad1,
                                               float* __restrict__ h1,
                                               float* __restrict__ a_s,
                                               float* __restrict__ a_d){
  __shared__ float w[DIN * C1];
  for (int i = threadIdx.x; i < DIN * C1; i += 256) w[i] = W[i];
  __syncthreads();
  int idx = blockIdx.x * 256 + threadIdx.x;
  int n = idx >> 5, j = idx & 31;           // j = h*4+f
  const float* xr = x + (size_t)n * DIN;
  float acc = 0.f;
  #pragma unroll
  for (int k = 0; k < DIN; ++k) acc += xr[k] * w[k * C1 + j];
  h1[idx] = acc;
  float s = acc * as1[j], d = acc * ad1[j];
  s += __shfl_xor(s, 1, 64); s += __shfl_xor(s, 2, 64);
  d += __shfl_xor(d, 1, 64); d += __shfl_xor(d, 2, 64);
  if ((j & 3) == 0){ a_s[n * H1 + (j >> 2)] = s; a_d[n * H1 + (j >> 2)] = d; }
}

// ---------- counting sort of edges by dst ----------
__global__ __launch_bounds__(256) void k_hist(const int* __restrict__ ei, int* __restrict__ cnt){
  int e = blockIdx.x * 256 + threadIdx.x;
  if (e >= ET) return;
  int s, d; edge_sd(ei, e, s, d);
  atomicAdd(&cnt[d], 1);
}

__global__ __launch_bounds__(256) void k_scan_blk(const int* __restrict__ cnt,
                                                  int* __restrict__ tmp, int* __restrict__ btot){
  int g = blockIdx.x * 256 + threadIdx.x;
  int v = (g < NN) ? cnt[g] : 0;
  int lane = threadIdx.x & 63, wv = threadIdx.x >> 6;
  int xv = v;
  #pragma unroll
  for (int o = 1; o < 64; o <<= 1){ int y = __shfl_up(xv, o, 64); if (lane >= o) xv += y; }
  __shared__ int ws[4];
  if (lane == 63) ws[wv] = xv;
  __syncthreads();
  int off = 0;
  for (int i = 0; i < wv; ++i) off += ws[i];
  xv += off;
  if (g < NN) tmp[g] = xv;                        // inclusive within block
  if (threadIdx.x == 255) btot[blockIdx.x] = xv;  // block total
}

__global__ __launch_bounds__(512) void k_scan_top(int* __restrict__ btot){
  int t = threadIdx.x;
  int v = (t < NB_SCAN) ? btot[t] : 0;
  int lane = t & 63, wv = t >> 6;
  int xv = v;
  #pragma unroll
  for (int o = 1; o < 64; o <<= 1){ int y = __shfl_up(xv, o, 64); if (lane >= o) xv += y; }
  __shared__ int ws[8];
  if (lane == 63) ws[wv] = xv;
  __syncthreads();
  int off = 0;
  for (int i = 0; i < wv; ++i) off += ws[i];
  xv += off;
  if (t < NB_SCAN) btot[t] = xv - v;              // exclusive block prefix
}

__global__ __launch_bounds__(256) void k_scan_fin(const int* __restrict__ cnt,
                                                  const int* __restrict__ tmp,
                                                  const int* __restrict__ btot,
                                                  int* __restrict__ row, int* __restrict__ cur){
  int g = blockIdx.x * 256 + threadIdx.x;
  if (g < NN){
    int ex = tmp[g] - cnt[g] + btot[g >> 8];
    row[g] = ex; cur[g] = ex;
  } else if (g == NN){
    row[NN] = ET;
  }
}

__global__ __launch_bounds__(256) void k_scatter(const int* __restrict__ ei,
                                                 int* __restrict__ cur, int* __restrict__ ssrc){
  int e = blockIdx.x * 256 + threadIdx.x;
  if (e >= ET) return;
  int s, d; edge_sd(ei, e, s, d);
  int pos = atomicAdd(&cur[d], 1);
  ssrc[pos] = s;
}

// ---------- layer-1 aggregation: half-wave (32 lanes) per node, 8-deep pipelined ----------
__global__ __launch_bounds__(256) void k_agg1(const int* __restrict__ row,
                                              const int* __restrict__ ssrc,
                                              const float* __restrict__ a_s,
                                              const float* __restrict__ a_d,
                                              const float* __restrict__ h1,
                                              const float* __restrict__ b1,
                                              float* __restrict__ out1){
  int wid  = (blockIdx.x * 256 + threadIdx.x) >> 6;
  int lane = threadIdx.x & 63;
  int node = wid * 2 + (lane >> 5);
  int l32 = lane & 31, h = l32 >> 2;
  float ad  = a_d[node * H1 + h];
  int beg = row[node], end = row[node + 1];
  float acc = 0.f, den = 0.f;
  for (int base = beg; base < end; base += 32){
    int cnt = end - base; if (cnt > 32) cnt = 32;
    int schunk = ssrc[base + (l32 < cnt ? l32 : 0)];
    #pragma unroll 1
    for (int k0 = 0; k0 < cnt; k0 += 8){
      float wv[8], hv[8];
      #pragma unroll
      for (int u = 0; u < 8; ++u){
        int kk = k0 + u;
        bool live = kk < cnt;
        int s = __shfl(schunk, live ? kk : 0, 32);
        float a = a_s[s * H1 + h];
        hv[u] = h1[s * C1 + l32];
        wv[u] = live ? __expf(lrelu(a + ad)) : 0.f;
      }
      #pragma unroll
      for (int u = 0; u < 8; ++u){ den += wv[u]; acc += wv[u] * hv[u]; }
    }
  }
  float v = acc / den + b1[l32];
  out1[node * C1 + l32] = v > 0.f ? v : expm1f(v);   // fused bias + ELU
}

// ---------- GEMM2 (out1@W2) fused with att2 dots ----------
__global__ __launch_bounds__(256) void k_gemm2(const float* __restrict__ hin,
                                               const float* __restrict__ W,
                                               const float* __restrict__ as2,
                                               const float* __restrict__ ad2,
                                               float* __restrict__ h2,
                                               float* __restrict__ a_s,
                                               float* __restrict__ a_d){
  __shared__ float w[C1 * DOUT];
  for (int i = threadIdx.x; i < C1 * DOUT; i += 256) w[i] = W[i];
  __syncthreads();
  int idx = blockIdx.x * 256 + threadIdx.x;
  int n = idx >> 6, j = idx & 63;
  const float* hr = hin + (size_t)n * C1;
  float acc = 0.f;
  #pragma unroll
  for (int k = 0; k < C1; ++k) acc += hr[k] * w[k * DOUT + j];
  h2[idx] = acc;
  float s = acc * as2[j], d = acc * ad2[j];
  #pragma unroll
  for (int o = 1; o < 64; o <<= 1){ s += __shfl_xor(s, o, 64); d += __shfl_xor(d, o, 64); }
  if (j == 0){ a_s[n] = s; a_d[n] = d; }
}

// ---------- layer-2 aggregation + mean-pool scatter: wave per node, 8-deep pipelined ----------
__global__ __launch_bounds__(256) void k_agg2(const int* __restrict__ row,
                                              const int* __restrict__ ssrc,
                                              const float* __restrict__ a_s,
                                              const float* __restrict__ a_d,
                                              const float* __restrict__ h2,
                                              const int* __restrict__ batch,
                                              float* __restrict__ sums,
                                              float* __restrict__ cntg){
  int node = (blockIdx.x * 256 + threadIdx.x) >> 6;
  int lane = threadIdx.x & 63;
  float ad  = a_d[node];
  int beg = row[node], end = row[node + 1];
  float acc = 0.f, den = 0.f;
  for (int base = beg; base < end; base += 64){
    int cnt = end - base; if (cnt > 64) cnt = 64;
    int schunk = ssrc[base + (lane < cnt ? lane : 0)];
    #pragma unroll 1
    for (int k0 = 0; k0 < cnt; k0 += 8){
      float wv[8], hv[8];
      #pragma unroll
      for (int u = 0; u < 8; ++u){
        int kk = k0 + u;
        bool live = kk < cnt;
        int s = __shfl(schunk, live ? kk : 0, 64);
        float a = a_s[s];
        hv[u] = h2[(size_t)s * DOUT + lane];
        wv[u] = live ? __expf(lrelu(a + ad)) : 0.f;
      }
      #pragma unroll
      for (int u = 0; u < 8; ++u){ den += wv[u]; acc += wv[u] * hv[u]; }
    }
  }
  float o = acc / den;
  int g = batch[node];
  atomicAdd(&sums[g * DOUT + lane], o);
  if (lane == 0) atomicAdd(&cntg[g], 1.f);
}

__global__ __launch_bounds__(256) void k_final(const float* __restrict__ sums,
                                               const float* __restrict__ cntg,
                                               const float* __restrict__ b2,
                                               float* __restrict__ out){
  int idx = blockIdx.x * 256 + threadIdx.x;
  if (idx >= NG * DOUT) return;
  int g = idx >> 6, f = idx & 63;
  out[idx] = sums[idx] / fmaxf(cntg[g], 1.f) + b2[f];
}

extern "C" void kernel_launch(void* const* d_in, const int* in_sizes, int n_in,
                              void* d_out, int out_size, void* d_ws, size_t ws_size,
                              hipStream_t stream) {
  const float* x   = (const float*)d_in[0];
  const int*   ei  = (const int*)  d_in[1];
  const int*   bat = (const int*)  d_in[2];
  const float* W1  = (const float*)d_in[3];
  const float* as1 = (const float*)d_in[4];
  const float* ad1 = (const float*)d_in[5];
  const float* b1  = (const float*)d_in[6];
  const float* W2  = (const float*)d_in[7];
  const float* as2 = (const float*)d_in[8];
  const float* ad2 = (const float*)d_in[9];
  const float* b2  = (const float*)d_in[10];
  float* out = (float*)d_out;

  float* p = (float*)d_ws;
  float* h1    = p; p += (size_t)NN * C1;       // 3.2M
  float* a_s1  = p; p += (size_t)NN * H1;       // 0.8M
  float* a_d1  = p; p += (size_t)NN * H1;
  float* out1  = p; p += (size_t)NN * C1;
  float* h2    = p; p += (size_t)NN * DOUT;     // 6.4M
  float* a_s2  = p; p += NN;
  float* a_d2  = p; p += NN;
  int*   row   = (int*)p; p += NN + 1;
  int*   cur   = (int*)p; p += NN;
  int*   tmp   = (int*)p; p += NN;
  int*   btot  = (int*)p; p += 512;
  int*   ssrc  = (int*)p; p += ET;              // 3.3M
  // zero-init region (histogram + pool accumulators)
  float* zbase = p;
  int*   cnt   = (int*)p; p += NN;
  float* sums  = p; p += NG * DOUT;
  float* cntg  = p; p += NG;
  size_t zbytes = (size_t)(p - zbase) * sizeof(float);

  hipMemsetAsync(zbase, 0, zbytes, stream);

  // node transforms
  k_gemm1<<<(NN * C1) / 256, 256, 0, stream>>>(x, W1, as1, ad1, h1, a_s1, a_d1);

  // counting sort by dst
  k_hist    <<<(ET + 255) / 256, 256, 0, stream>>>(ei, cnt);
  k_scan_blk<<<NB_SCAN, 256, 0, stream>>>(cnt, tmp, btot);
  k_scan_top<<<1, 512, 0, stream>>>(btot);
  k_scan_fin<<<(NN + 256) / 256, 256, 0, stream>>>(cnt, tmp, btot, row, cur);
  k_scatter <<<(ET + 255) / 256, 256, 0, stream>>>(ei, cur, ssrc);

  // layer 1 aggregate (+bias+ELU)
  k_agg1<<<(NN * 32) / 256, 256, 0, stream>>>(row, ssrc, a_s1, a_d1, h1, b1, out1);

  // layer 2
  k_gemm2<<<(NN * DOUT) / 256, 256, 0, stream>>>(out1, W2, as2, ad2, h2, a_s2, a_d2);
  k_agg2 <<<(NN * DOUT) / 256, 256, 0, stream>>>(row, ssrc, a_s2, a_d2, h2, bat, sums, cntg);

  // finalize pooled means
  k_final<<<(NG * DOUT + 255) / 256, 256, 0, stream>>>(sums, cntg, b2, out);
}